// Round 17
// baseline (140.756 us; speedup 1.0000x reference)
//
#include <hip/hip_runtime.h>
#include <math.h>

// PONITA fixed-size: B=1, N=256, NUM_ORI=16, H=64, BD=32, WF*H=256, L=2
#define NPTS 256
#define NORI 16
#define CH   64
#define BD   32
#define HID  64
#define STEP16 0.39269908169872414f

typedef __bf16 bf16x8 __attribute__((ext_vector_type(8)));
typedef float  f32x4  __attribute__((ext_vector_type(4)));

#define MFMA16(a, b, cc) __builtin_amdgcn_mfma_f32_16x16x32_bf16(a, b, cc, 0, 0, 0)

__device__ __forceinline__ float gelu_f(float x) {
    float x2 = x * x;
    float y2 = x * fmaf(0.07135481627f, x2, 1.5957691216f);   // 2y
    float e = __expf(y2);
    return x - x * __builtin_amdgcn_rcpf(e + 1.0f);           // x*(1 - 1/(e+1))
}

__device__ __forceinline__ unsigned pk2(float x, float y) {
    union { __bf16 h[2]; unsigned u; } r;
    r.h[0] = (__bf16)x; r.h[1] = (__bf16)y;
    return r.u;
}

// ================= device helpers =================
__device__ __forceinline__ void dev_prep(
    const float* __restrict__ skb_W1, const float* __restrict__ skb_W2,
    const float* __restrict__ conv_sW,
    __bf16* __restrict__ w1T, __bf16* __restrict__ w2T, __bf16* __restrict__ w2Tlo,
    __bf16* __restrict__ sWT, __bf16* __restrict__ sWTlo, int t)
{
    if (t < 64) {
        float f[9];
        f[0] = skb_W1[t];
        f[1] = skb_W1[64 + t];
        f[2] = skb_W1[128 + t];
        f[3] = skb_W1[192 + t] + skb_W1[256 + t];
        f[4] = skb_W1[320 + t];
        f[5] = skb_W1[384 + t];
        f[6] = skb_W1[448 + t] + skb_W1[512 + t] + skb_W1[640 + t];
        f[7] = skb_W1[576 + t] + skb_W1[704 + t] + skb_W1[768 + t];
        f[8] = skb_W1[832 + t];
#pragma unroll
        for (int k = 0; k < 9; ++k) {
            __bf16 hi = (__bf16)f[k];
            w1T[t * 32 + k]      = hi;
            w1T[t * 32 + 9 + k]  = (__bf16)(f[k] - (float)hi);
            w1T[t * 32 + 18 + k] = hi;
        }
#pragma unroll
        for (int k = 27; k < 32; ++k) w1T[t * 32 + k] = (__bf16)0.0f;
    }
    for (int i = t; i < 2048; i += 256) {
        int n = i >> 6, kk = i & 63;
        float v = skb_W2[kk * 32 + n];
        __bf16 hi = (__bf16)v;
        w2T[i]   = hi;
        w2Tlo[i] = (__bf16)(v - (float)hi);
    }
    for (int i = t; i < 4096; i += 256) {
        int ll = i >> 11, chh = (i >> 5) & 63, k = i & 31;
        float v = conv_sW[(ll * 32 + k) * 64 + chh];
        __bf16 hi = (__bf16)v;
        sWT[i]   = hi;
        sWTlo[i] = (__bf16)(v - (float)hi);
    }
}

__device__ __forceinline__ void dev_fiber(
    const float* __restrict__ rkb_W1, const float* __restrict__ rkb_b1,
    const float* __restrict__ rkb_W2, const float* __restrict__ rkb_b2,
    const float* __restrict__ conv_rW, float* __restrict__ rk, int p, int t)
{
    __shared__ float w1L[3 * 64], b1L[64], w2L[64 * 32], b2L[32];
    __shared__ float rwL[2 * 32 * 64];
    __shared__ float t1L[16 * 64];
    __shared__ float fbL[16 * 32];

    if (t < 192) w1L[t] = rkb_W1[t];
    if (t >= 192 && t < 256) b1L[t - 192] = rkb_b1[t - 192];
    for (int i = t; i < 2048; i += 256) w2L[i] = rkb_W2[i];
    if (t < 32) b2L[t] = rkb_b2[t];
    for (int i = t; i < 4096; i += 256) rwL[i] = conv_rW[i];
    __syncthreads();

    const int o = t & 15;
    const float cp = cosf(p * STEP16), sp = sinf(p * STEP16);
    const float co = cosf(o * STEP16), so = sinf(o * STEP16);
    const float s0 = cp * co + sp * so;
    const float m1 = s0 * s0, m2 = m1 * s0;

    {
        const int jg = t >> 4;
#pragma unroll
        for (int u = 0; u < 4; ++u) {
            const int j = jg * 4 + u;
            float a = b1L[j] + s0 * w1L[j] + m1 * w1L[64 + j] + m2 * w1L[128 + j];
            t1L[o * 64 + j] = gelu_f(a);
        }
    }
    __syncthreads();
    {
        const int kg = t >> 4;
#pragma unroll
        for (int kk = 0; kk < 2; ++kk) {
            const int k = kg + kk * 16;
            float a = b2L[k];
#pragma unroll
            for (int j = 0; j < 64; ++j) a += t1L[o * 64 + j] * w2L[j * 32 + k];
            fbL[o * 32 + k] = gelu_f(a);
        }
    }
    __syncthreads();
    {
        const int o2 = t >> 4;
        const int chg = (t & 15) * 4;
#pragma unroll
        for (int l = 0; l < 2; ++l) {
            f32x4 acc = {0.f, 0.f, 0.f, 0.f};
#pragma unroll
            for (int k = 0; k < 32; ++k) {
                const float fv = fbL[o2 * 32 + k];
                const f32x4 rv = *(const f32x4*)(rwL + (l * 32 + k) * 64 + chg);
                acc[0] = fmaf(fv, rv[0], acc[0]);
                acc[1] = fmaf(fv, rv[1], acc[1]);
                acc[2] = fmaf(fv, rv[2], acc[2]);
                acc[3] = fmaf(fv, rv[3], acc[3]);
            }
            *(f32x4*)(rk + (l * 256 + p * 16 + o2) * 64 + chg) = acc;
        }
    }
}

// ================= standalone small kernels =================
__global__ __launch_bounds__(256) void k_prep(
    const float* __restrict__ skb_W1, const float* __restrict__ skb_W2,
    const float* __restrict__ conv_sW,
    __bf16* __restrict__ w1T, __bf16* __restrict__ w2T, __bf16* __restrict__ w2Tlo,
    __bf16* __restrict__ sWT, __bf16* __restrict__ sWTlo)
{
    dev_prep(skb_W1, skb_W2, conv_sW, w1T, w2T, w2Tlo, sWT, sWTlo, threadIdx.x);
}

__global__ __launch_bounds__(256) void k_fiber2(
    const float* __restrict__ rkb_W1, const float* __restrict__ rkb_b1,
    const float* __restrict__ rkb_W2, const float* __restrict__ rkb_b2,
    const float* __restrict__ conv_rW, float* __restrict__ rk)
{
    dev_fiber(rkb_W1, rkb_b1, rkb_W2, rkb_b2, conv_rW, rk, blockIdx.x, threadIdx.x);
}

// old-layout h init (fallback path): h[n][o][ch]
__global__ __launch_bounds__(256) void k_init(
    const float* __restrict__ x, const float* __restrict__ emb_W, float* __restrict__ h)
{
    int idx = blockIdx.x * 256 + threadIdx.x;
    int ch = idx & 63;
    int n  = idx >> 10;
    h[idx] = x[n * 3] * emb_W[ch] + x[n * 3 + 1] * emb_W[64 + ch] + x[n * 3 + 2] * emb_W[128 + ch];
}

// fused setup (fast path): blocks [0,1024) init h2[n][ch][o]; [1024,1040) fiber; 1040 prep
__global__ __launch_bounds__(256) void k_setup(
    const float* __restrict__ x, const float* __restrict__ emb_W, float* __restrict__ h2,
    const float* __restrict__ rkb_W1, const float* __restrict__ rkb_b1,
    const float* __restrict__ rkb_W2, const float* __restrict__ rkb_b2,
    const float* __restrict__ conv_rW, float* __restrict__ rk,
    const float* __restrict__ skb_W1, const float* __restrict__ skb_W2,
    const float* __restrict__ conv_sW,
    __bf16* __restrict__ w1T, __bf16* __restrict__ w2T, __bf16* __restrict__ w2Tlo,
    __bf16* __restrict__ sWT, __bf16* __restrict__ sWTlo)
{
    const int b = blockIdx.x, t = threadIdx.x;
    if (b < 1024) {
        int idx = b * 256 + t;                  // (n*64+ch)*16 + o
        int ch = (idx >> 4) & 63;
        int n  = idx >> 10;
        h2[idx] = x[n * 3] * emb_W[ch] + x[n * 3 + 1] * emb_W[64 + ch]
                + x[n * 3 + 2] * emb_W[128 + ch];
    } else if (b < 1040) {
        dev_fiber(rkb_W1, rkb_b1, rkb_W2, rkb_b2, conv_rW, rk, b - 1024, t);
    } else {
        dev_prep(skb_W1, skb_W2, conv_sW, w1T, w2T, w2Tlo, sWT, sWTlo, t);
    }
}

// ================= kb materialization: symmetry + transposed GEMMs, SINGLE COPY ==========
// kb(m,n,o) == kb(n,m,o^8) exactly. Store ONLY the canonical o<8 copy:
// kb_g[(m*256+n)*8 + o] (64B rows, chunk-swizzled by o&3). 32 MB total, writes halved;
// conv reads o>=8 lanes from kb_g[(n*256+m)*8 + (o-8)] -- same bits, bit-identical.
__global__ __launch_bounds__(256) void k_kb2(
    const float* __restrict__ pos,
    const float* __restrict__ skb_b1, const float* __restrict__ skb_b2,
    const __bf16* __restrict__ w1T, const __bf16* __restrict__ w2T,
    const __bf16* __restrict__ w2Tlo, __bf16* __restrict__ kb_g)
{
    const int t = threadIdx.x;
    const int c = t & 15, qq = (t >> 4) & 3, w = t >> 6;
    const int b = blockIdx.x;
    const int pair = b >> 2;
    const int ohalf = (b >> 1) & 1;
    const int mhalf = b & 1;
    const int m0 = (pair >> 4) * 16, n0 = (pair & 15) * 16;

    bf16x8 w1B[4], w2A[2][2], w2Alo[2][2];
    float b1x[4][4], b2x[2][4];
#pragma unroll
    for (int ni = 0; ni < 4; ++ni) {
        w1B[ni] = *(const bf16x8*)(w1T + (ni * 16 + c) * 32 + qq * 8);
#pragma unroll
        for (int r = 0; r < 4; ++r) b1x[ni][r] = skb_b1[ni * 16 + qq * 4 + r];
    }
#pragma unroll
    for (int mk = 0; mk < 2; ++mk) {
#pragma unroll
        for (int ks = 0; ks < 2; ++ks) {
            w2A[mk][ks]   = *(const bf16x8*)(w2T   + (mk * 16 + c) * 64 + ks * 32 + qq * 8);
            w2Alo[mk][ks] = *(const bf16x8*)(w2Tlo + (mk * 16 + c) * 64 + ks * 32 + qq * 8);
        }
#pragma unroll
        for (int r = 0; r < 4; ++r) b2x[mk][r] = skb_b2[mk * 16 + qq * 4 + r];
    }

    const int n = n0 + c;
    const float pnx = pos[2 * n], pny = pos[2 * n + 1];
    float cosv[4], sinv[4];
#pragma unroll
    for (int oi = 0; oi < 4; ++oi) {
        float th = (float)(ohalf * 4 + oi) * STEP16;
        cosv[oi] = cosf(th); sinv[oi] = sinf(th);
    }
    const int s0lane = c + ((qq & 1) << 5);
    const int s1lane = s0lane + 16;
    const int selhi = qq >> 1;
    const f32x4 zf = {0.f, 0.f, 0.f, 0.f};

#pragma unroll 1
    for (int mi2 = 0; mi2 < 2; ++mi2) {
        const int m = m0 + w * 4 + mhalf * 2 + mi2;
        const float dx = pnx - pos[2 * m];
        const float dy = pny - pos[2 * m + 1];
#pragma unroll
        for (int oi = 0; oi < 4; ++oi) {
            const int o = ohalf * 4 + oi;
            float a = dx * cosv[oi] + dy * sinv[oi];
            float vx = dx - dx * a, vy = dy - dy * a;
            float b2 = sqrtf(vx * vx + vy * vy);
            float mfv[9];
            mfv[0] = a; mfv[1] = b2; mfv[2] = a * a; mfv[3] = a * b2; mfv[4] = b2 * b2;
            mfv[5] = mfv[2] * a; mfv[6] = mfv[2] * b2; mfv[7] = mfv[3] * b2; mfv[8] = mfv[4] * b2;
            __bf16 mh[9], ml[9];
#pragma unroll
            for (int i = 0; i < 9; ++i) {
                mh[i] = (__bf16)mfv[i];
                ml[i] = (__bf16)(mfv[i] - (float)mh[i]);
            }
            bf16x8 mb;
            if (qq == 0) {
                mb[0]=mh[0]; mb[1]=mh[1]; mb[2]=mh[2]; mb[3]=mh[3];
                mb[4]=mh[4]; mb[5]=mh[5]; mb[6]=mh[6]; mb[7]=mh[7];
            } else if (qq == 1) {
                mb[0]=mh[8]; mb[1]=mh[0]; mb[2]=mh[1]; mb[3]=mh[2];
                mb[4]=mh[3]; mb[5]=mh[4]; mb[6]=mh[5]; mb[7]=mh[6];
            } else if (qq == 2) {
                mb[0]=mh[7]; mb[1]=mh[8]; mb[2]=ml[0]; mb[3]=ml[1];
                mb[4]=ml[2]; mb[5]=ml[3]; mb[6]=ml[4]; mb[7]=ml[5];
            } else {
                mb[0]=ml[6]; mb[1]=ml[7]; mb[2]=ml[8]; mb[3]=(__bf16)0.0f;
                mb[4]=(__bf16)0.0f; mb[5]=(__bf16)0.0f; mb[6]=(__bf16)0.0f; mb[7]=(__bf16)0.0f;
            }

            unsigned t1p[4][2];
#pragma unroll
            for (int ni = 0; ni < 4; ++ni) {
                f32x4 acc = MFMA16(w1B[ni], mb, zf);
                float g0 = gelu_f(acc[0] + b1x[ni][0]);
                float g1 = gelu_f(acc[1] + b1x[ni][1]);
                float g2 = gelu_f(acc[2] + b1x[ni][2]);
                float g3 = gelu_f(acc[3] + b1x[ni][3]);
                t1p[ni][0] = pk2(g0, g1);
                t1p[ni][1] = pk2(g2, g3);
            }

            bf16x8 B2[2];
#pragma unroll
            for (int ks = 0; ks < 2; ++ks) {
                const unsigned lo0 = t1p[ks * 2][0],     lo1 = t1p[ks * 2][1];
                const unsigned hi0 = t1p[ks * 2 + 1][0], hi1 = t1p[ks * 2 + 1][1];
                unsigned aL0 = (unsigned)__shfl((int)lo0, s0lane);
                unsigned aL1 = (unsigned)__shfl((int)lo1, s0lane);
                unsigned aL2 = (unsigned)__shfl((int)lo0, s1lane);
                unsigned aL3 = (unsigned)__shfl((int)lo1, s1lane);
                unsigned aH0 = (unsigned)__shfl((int)hi0, s0lane);
                unsigned aH1 = (unsigned)__shfl((int)hi1, s0lane);
                unsigned aH2 = (unsigned)__shfl((int)hi0, s1lane);
                unsigned aH3 = (unsigned)__shfl((int)hi1, s1lane);
                union { unsigned u[4]; bf16x8 v; } bu;
                bu.u[0] = selhi ? aH0 : aL0;
                bu.u[1] = selhi ? aH1 : aL1;
                bu.u[2] = selhi ? aH2 : aL2;
                bu.u[3] = selhi ? aH3 : aL3;
                B2[ks] = bu.v;
            }

            const size_t ptP = (size_t)(m * 256 + n) * 8 + o;   // canonical copy only
            const int swz = o & 3;
#pragma unroll
            for (int mk = 0; mk < 2; ++mk) {
                f32x4 acc = MFMA16(w2A[mk][0], B2[0], zf);
                acc = MFMA16(w2A[mk][1], B2[1], acc);
                acc = MFMA16(w2Alo[mk][0], B2[0], acc);
                acc = MFMA16(w2Alo[mk][1], B2[1], acc);
                float g0 = gelu_f(acc[0] + b2x[mk][0]);
                float g1 = gelu_f(acc[1] + b2x[mk][1]);
                float g2 = gelu_f(acc[2] + b2x[mk][2]);
                float g3 = gelu_f(acc[3] + b2x[mk][3]);
                uint2 pv; pv.x = pk2(g0, g1); pv.y = pk2(g2, g3);
                const int off = (((mk * 2 + (qq >> 1)) ^ swz) << 4) + ((qq & 1) << 3);
                *(uint2*)((char*)kb_g + ptP * 64 + off) = pv;
            }
        }
    }
}

// ================= conv layer v7: register stream, HALF-SIZE kb (mirror read) ==========
// Lane c = orientation o. o<8: read kb_g[m][n][o]; o>=8: read kb_g[n][m][o-8] (same
// bits by exact symmetry). Each wave: two contiguous 512B segments per tile.
// h layout [n][ch][o] (h2). LDS used only by the epilogue.
__global__ __launch_bounds__(1024) void k_conv7(
    const __bf16* __restrict__ kb_g,
    const __bf16* __restrict__ sWT, const __bf16* __restrict__ sWTlo,
    const float* __restrict__ conv_b, const float* __restrict__ rkg,
    const float* __restrict__ ln_scale, const float* __restrict__ ln_bias,
    const float* __restrict__ lin1_W, const float* __restrict__ lin1_b,
    const float* __restrict__ lin2_W, const float* __restrict__ lin2_b,
    const float* __restrict__ h_in, float* __restrict__ h_out, int l)
{
    __shared__ __align__(16) unsigned char smem[90112];
    const int t = threadIdx.x;
    const int m = blockIdx.x;
    const int w = t >> 6, lane = t & 63;
    const int qq = lane >> 4, c = lane & 15;
    const f32x4 zf = {0.f, 0.f, 0.f, 0.f};

    bf16x8 sWB[4], sWBlo[4];
#pragma unroll
    for (int ni = 0; ni < 4; ++ni) {
        sWB[ni]   = *(const bf16x8*)(sWT   + l * 2048 + (ni * 16 + c) * 32 + qq * 8);
        sWBlo[ni] = *(const bf16x8*)(sWTlo + l * 2048 + (ni * 16 + c) * 32 + qq * 8);
    }

    f32x4 cacc[4];
#pragma unroll
    for (int ni = 0; ni < 4; ++ni)
#pragma unroll
        for (int r = 0; r < 4; ++r) cacc[ni][r] = 0.f;

    // per-lane kb source: o = c. primary (c<8): point m*2048 + n*8 + c, tile step 128 pts.
    // mirror (c>=8): point n*2048 + m*8 + (c-8), tile step 16*2048 pts. n0 = w.
    size_t lp, tsb;
    if (c < 8) { lp = (size_t)m * 2048 + (size_t)w * 8 + c;          tsb = 128ull * 64; }
    else       { lp = (size_t)w * 2048 + (size_t)m * 8 + (c - 8);    tsb = 32768ull * 64; }
    const char* kbsrc = (const char*)kb_g + lp * 64 + ((qq ^ (c & 3)) << 4);
    const float* hbase = h_in + c * 16 + qq * 4;   // + n*1024 + ni*256

    // ---- prologue: issue groups for tiles 0 and 1 (5 loads each) ----
    bf16x8 kbf[2];
    f32x4 hbf[2][4];
    kbf[0] = *(const bf16x8*)(kbsrc);
    {
        const float* hp = hbase + (0 * 16 + w) * 1024;
        hbf[0][0] = *(const f32x4*)(hp);
        hbf[0][1] = *(const f32x4*)(hp + 256);
        hbf[0][2] = *(const f32x4*)(hp + 512);
        hbf[0][3] = *(const f32x4*)(hp + 768);
    }
    kbf[1] = *(const bf16x8*)(kbsrc + tsb);
    {
        const float* hp = hbase + (1 * 16 + w) * 1024;
        hbf[1][0] = *(const f32x4*)(hp);
        hbf[1][1] = *(const f32x4*)(hp + 256);
        hbf[1][2] = *(const f32x4*)(hp + 512);
        hbf[1][3] = *(const f32x4*)(hp + 768);
    }

#pragma unroll
    for (int tile = 0; tile < 16; ++tile) {
        const int bi = tile & 1;
        if (tile < 15) { asm volatile("s_waitcnt vmcnt(5)" ::: "memory"); }
        else           { asm volatile("s_waitcnt vmcnt(0)" ::: "memory"); }
        __builtin_amdgcn_sched_barrier(0);

        const bf16x8 aF = kbf[bi];
        f32x4 g;
#pragma unroll
        for (int ni = 0; ni < 4; ++ni) {
            g = MFMA16(aF, sWB[ni], zf);
            g = MFMA16(aF, sWBlo[ni], g);
#pragma unroll
            for (int r = 0; r < 4; ++r)
                cacc[ni][r] = fmaf(g[r], hbf[bi][ni][r], cacc[ni][r]);
        }

        if (tile < 14) {
            kbf[bi] = *(const bf16x8*)(kbsrc + (size_t)(tile + 2) * tsb);
            const float* hp = hbase + ((tile + 2) * 16 + w) * 1024;
            hbf[bi][0] = *(const f32x4*)(hp);
            hbf[bi][1] = *(const f32x4*)(hp + 256);
            hbf[bi][2] = *(const f32x4*)(hp + 512);
            hbf[bi][3] = *(const f32x4*)(hp + 768);
        }
    }
    __syncthreads();

    // ---- partial c1 per wave -> LDS ----
    {
        float* c1p = (float*)smem;
#pragma unroll
        for (int ni = 0; ni < 4; ++ni)
#pragma unroll
            for (int r = 0; r < 4; ++r)
                c1p[w * 1024 + (qq * 4 + r) * 64 + ni * 16 + c] = cacc[ni][r];
    }
    __syncthreads();
    {
        float* c1p = (float*)smem;
        float* c1r = (float*)(smem + 65536);
        float s = 0.f;
#pragma unroll
        for (int ww = 0; ww < 16; ++ww) s += c1p[ww * 1024 + t];
        c1r[t] = s;
    }
    __syncthreads();

    // ---- orientation mixing + bias + LayerNorm (wave w = p, lane = ch) ----
    {
        float* c1r = (float*)(smem + 65536);
        float* cns = (float*)(smem + 69632);
        const int ch = lane;
        const float cb  = conv_b[l * 64 + ch];
        const float lsc = ln_scale[l * 64 + ch], lbi = ln_bias[l * 64 + ch];
        const float* rkp = rkg + (l * 256 + w * 16) * 64 + ch;
        float s = cb;
#pragma unroll
        for (int o = 0; o < 16; ++o) s += c1r[o * 64 + ch] * rkp[o * 64];
        float red = s;
#pragma unroll
        for (int off = 32; off > 0; off >>= 1) red += __shfl_xor(red, off);
        float mu = red * (1.0f / 64.0f);
        float d = s - mu;
        float r2 = d * d;
#pragma unroll
        for (int off = 32; off > 0; off >>= 1) r2 += __shfl_xor(r2, off);
        cns[w * 64 + ch] = d * rsqrtf(r2 * (1.0f / 64.0f) + 1e-6f) * lsc + lbi;
    }
    __syncthreads();

    // ---- lin1 ----
    {
        float* cns = (float*)(smem + 69632);
        float* usS = (float*)(smem + 73728);
        const int j = t & 255, q4 = t >> 8;
        const float* W1l = lin1_W + l * 64 * 256;
        const float bl1 = lin1_b[l * 256 + j];
        float ua[4];
#pragma unroll
        for (int pi = 0; pi < 4; ++pi) ua[pi] = bl1;
#pragma unroll 4
        for (int c2 = 0; c2 < 64; ++c2) {
            const float wv = W1l[c2 * 256 + j];
#pragma unroll
            for (int pi = 0; pi < 4; ++pi)
                ua[pi] = fmaf(cns[(q4 * 4 + pi) * 64 + c2], wv, ua[pi]);
        }
#pragma unroll
        for (int pi = 0; pi < 4; ++pi) usS[(q4 * 4 + pi) * 256 + j] = gelu_f(ua[pi]);
    }
    __syncthreads();

    // ---- lin2 + residual (h2 layout [n][ch][o]) ----
    {
        float* usS = (float*)(smem + 73728);
        const int ch2 = t & 63, pg = t >> 6;
        const float* W2l = lin2_W + l * 256 * 64;
        float o0 = lin2_b[l * 64 + ch2];
#pragma unroll 4
        for (int j = 0; j < 256; ++j)
            o0 = fmaf(usS[pg * 256 + j], W2l[j * 64 + ch2], o0);
        const int i0 = m * 1024 + ch2 * 16 + pg;
        h_out[i0] = h_in[i0] + o0;
    }
}

// ================= fallback conv layer (old layout), verbatim from passing round ========
__global__ __launch_bounds__(512, 1) void k_layer2(
    const float* __restrict__ pos,
    const float* __restrict__ skb_b1, const float* __restrict__ skb_b2,
    const __bf16* __restrict__ w1T, const __bf16* __restrict__ w2T,
    const __bf16* __restrict__ w2Tlo,
    const __bf16* __restrict__ sWT, const __bf16* __restrict__ sWTlo,
    const float* __restrict__ conv_b, const float* __restrict__ rkg,
    const float* __restrict__ ln_scale, const float* __restrict__ ln_bias,
    const float* __restrict__ lin1_W, const float* __restrict__ lin1_b,
    const float* __restrict__ lin2_W, const float* __restrict__ lin2_b,
    const float* __restrict__ h_in, float* __restrict__ h_out, int l)
{
    __shared__ __align__(16) unsigned char smem[57344];
    const int t = threadIdx.x;
    const int m = blockIdx.x;
    const int w = t >> 6, lane = t & 63;
    const int qq = lane >> 4, c = lane & 15;

    bf16x8 w1B[4], sWB[4], sWBlo[4], w2B[2][2], w2Blo[2][2];
    float b1v[4], b2v[2];
#pragma unroll
    for (int ni = 0; ni < 4; ++ni) {
        w1B[ni]   = *(const bf16x8*)(w1T + (ni * 16 + c) * 32 + qq * 8);
        sWB[ni]   = *(const bf16x8*)(sWT   + l * 2048 + (ni * 16 + c) * 32 + qq * 8);
        sWBlo[ni] = *(const bf16x8*)(sWTlo + l * 2048 + (ni * 16 + c) * 32 + qq * 8);
        b1v[ni] = skb_b1[ni * 16 + c];
    }
#pragma unroll
    for (int nt = 0; nt < 2; ++nt) {
        b2v[nt] = skb_b2[nt * 16 + c];
#pragma unroll
        for (int ks = 0; ks < 2; ++ks) {
            w2B[nt][ks]   = *(const bf16x8*)(w2T   + (nt * 16 + c) * 64 + ks * 32 + qq * 8);
            w2Blo[nt][ks] = *(const bf16x8*)(w2Tlo + (nt * 16 + c) * 64 + ks * 32 + qq * 8);
        }
    }

    const float pmx = pos[2 * m], pmy = pos[2 * m + 1];
    float co_ = 0.f, so_ = 0.f;
    if (t < 256) { float th = (float)(t & 15) * STEP16; co_ = cosf(th); so_ = sinf(th); }

    f32x4 cacc[4];
#pragma unroll
    for (int ni = 0; ni < 4; ++ni)
#pragma unroll
        for (int r = 0; r < 4; ++r) cacc[ni][r] = 0.f;

#pragma unroll 1
    for (int tile = 0; tile < 16; ++tile) {
        if (t < 256) {
            const int n = tile * 16 + (t >> 4);
            float dx = pos[2 * n] - pmx, dy = pos[2 * n + 1] - pmy;
            float a = dx * co_ + dy * so_;
            float vx = dx - dx * a, vy = dy - dy * a;
            float b = sqrtf(vx * vx + vy * vy);
            float mf[9];
            mf[0] = a; mf[1] = b; mf[2] = a * a; mf[3] = a * b; mf[4] = b * b;
            mf[5] = mf[2] * a; mf[6] = mf[2] * b; mf[7] = mf[3] * b; mf[8] = mf[4] * b;
            __bf16 s[32];
#pragma unroll
            for (int i = 0; i < 9; ++i) {
                __bf16 hi = (__bf16)mf[i];
                s[i] = hi; s[9 + i] = hi;
                s[18 + i] = (__bf16)(mf[i] - (float)hi);
            }
#pragma unroll
            for (int i = 27; i < 32; ++i) s[i] = (__bf16)0.0f;
            unsigned char* rowp = smem + t * 64;
#pragma unroll
            for (int u = 0; u < 4; ++u) {
                bf16x8 vv;
#pragma unroll
                for (int j = 0; j < 8; ++j) vv[j] = s[u * 8 + j];
                *(bf16x8*)(rowp + ((u ^ (t & 3)) << 4)) = vv;
            }
        }
        __syncthreads();

#pragma unroll
        for (int mm = 0; mm < 2; ++mm) {
            const int row = (2 * w + mm) * 16 + c;
            bf16x8 aF = *(const bf16x8*)(smem + row * 64 + ((qq ^ (row & 3)) << 4));
#pragma unroll
            for (int ni = 0; ni < 4; ++ni) {
                f32x4 acc = {0.f, 0.f, 0.f, 0.f};
                acc = MFMA16(aF, w1B[ni], acc);
#pragma unroll
                for (int r = 0; r < 4; ++r) {
                    const int ro = (2 * w + mm) * 16 + qq * 4 + r;
                    float g = gelu_f(acc[r] + b1v[ni]);
                    const int chc = ni * 16 + c;
                    *(__bf16*)(smem + 16384 + ro * 128 + (((chc >> 3) ^ (ro & 7)) << 4)
                               + ((chc & 7) << 1)) = (__bf16)g;
                }
            }
        }
        __syncthreads();

#pragma unroll
        for (int mm = 0; mm < 2; ++mm) {
            const int row = (2 * w + mm) * 16 + c;
            bf16x8 a0 = *(const bf16x8*)(smem + 16384 + row * 128 + ((qq ^ (row & 7)) << 4));
            bf16x8 a1 = *(const bf16x8*)(smem + 16384 + row * 128 + (((4 + qq) ^ (row & 7)) << 4));
#pragma unroll
            for (int nt = 0; nt < 2; ++nt) {
                f32x4 acc = {0.f, 0.f, 0.f, 0.f};
                acc = MFMA16(a0, w2B[nt][0], acc);
                acc = MFMA16(a1, w2B[nt][1], acc);
                acc = MFMA16(a0, w2Blo[nt][0], acc);
                acc = MFMA16(a1, w2Blo[nt][1], acc);
#pragma unroll
                for (int r = 0; r < 4; ++r) {
                    const int ro = (2 * w + mm) * 16 + qq * 4 + r;
                    float g = gelu_f(acc[r] + b2v[nt]);
                    const int kc = nt * 16 + c;
                    *(__bf16*)(smem + ro * 64 + (((kc >> 3) ^ (ro & 3)) << 4)
                               + ((kc & 7) << 1)) = (__bf16)g;
                }
            }
        }
        __syncthreads();

#pragma unroll
        for (int mm = 0; mm < 2; ++mm) {
            const int mi = 2 * w + mm;
            const int row = mi * 16 + c;
            bf16x8 aF = *(const bf16x8*)(smem + row * 64 + ((qq ^ (row & 3)) << 4));
            const int nbase = (tile * 16 + mi) * 1024 + qq * 256;
#pragma unroll
            for (int ni = 0; ni < 4; ++ni) {
                f32x4 g3 = {0.f, 0.f, 0.f, 0.f};
                g3 = MFMA16(aF, sWB[ni], g3);
                g3 = MFMA16(aF, sWBlo[ni], g3);
#pragma unroll
                for (int r = 0; r < 4; ++r) {
                    float hv = h_in[nbase + r * 64 + ni * 16 + c];
                    cacc[ni][r] = fmaf(g3[r], hv, cacc[ni][r]);
                }
            }
        }
        __syncthreads();
    }

    {
        float* c1p = (float*)smem;
#pragma unroll
        for (int ni = 0; ni < 4; ++ni)
#pragma unroll
            for (int r = 0; r < 4; ++r)
                c1p[w * 1024 + (qq * 4 + r) * 64 + ni * 16 + c] = cacc[ni][r];
    }
    __syncthreads();
    {
        float* c1p = (float*)smem;
        float* c1r = (float*)(smem + 32768);
        for (int i = t; i < 1024; i += 512) {
            float s = 0.f;
#pragma unroll
            for (int ww = 0; ww < 8; ++ww) s += c1p[ww * 1024 + i];
            c1r[i] = s;
        }
    }
    __syncthreads();

    {
        float* c1r = (float*)(smem + 32768);
        float* cns = (float*)(smem + 36864);
        const int ch = lane;
        const float cb  = conv_b[l * 64 + ch];
        const float lsc = ln_scale[l * 64 + ch], lbi = ln_bias[l * 64 + ch];
#pragma unroll
        for (int pp = 0; pp < 2; ++pp) {
            const int p = w + pp * 8;
            const float* rkp = rkg + (l * 256 + p * 16) * 64 + ch;
            float s = cb;
#pragma unroll
            for (int o = 0; o < 16; ++o) s += c1r[o * 64 + ch] * rkp[o * 64];
            float red = s;
#pragma unroll
            for (int off = 32; off > 0; off >>= 1) red += __shfl_xor(red, off);
            float mu = red * (1.0f / 64.0f);
            float d = s - mu;
            float r2 = d * d;
#pragma unroll
            for (int off = 32; off > 0; off >>= 1) r2 += __shfl_xor(r2, off);
            cns[p * 64 + ch] = d * rsqrtf(r2 * (1.0f / 64.0f) + 1e-6f) * lsc + lbi;
        }
    }
    __syncthreads();

    {
        float* cns = (float*)(smem + 36864);
        float* usS = (float*)(smem + 40960);
        const int j = t & 255, half = t >> 8;
        const float* W1l = lin1_W + l * 64 * 256;
        const float bl1 = lin1_b[l * 256 + j];
        float ua[8];
#pragma unroll
        for (int pi = 0; pi < 8; ++pi) ua[pi] = bl1;
#pragma unroll 1
        for (int c2 = 0; c2 < 64; ++c2) {
            const float wv = W1l[c2 * 256 + j];
#pragma unroll
            for (int pi = 0; pi < 8; ++pi)
                ua[pi] = fmaf(cns[(half * 8 + pi) * 64 + c2], wv, ua[pi]);
        }
#pragma unroll
        for (int pi = 0; pi < 8; ++pi) usS[(half * 8 + pi) * 256 + j] = gelu_f(ua[pi]);
    }
    __syncthreads();

    {
        float* usS = (float*)(smem + 40960);
        const int ch2 = t & 63, pg = t >> 6;
        const float* W2l = lin2_W + l * 256 * 64;
        const float bl2 = lin2_b[l * 64 + ch2];
        float o0 = bl2, o1 = bl2;
#pragma unroll 2
        for (int j = 0; j < 256; ++j) {
            const float wv = W2l[j * 64 + ch2];
            o0 = fmaf(usS[pg * 256 + j], wv, o0);
            o1 = fmaf(usS[(pg + 8) * 256 + j], wv, o1);
        }
        const int i0 = (m * 16 + pg) * 64 + ch2;
        const int i1 = (m * 16 + pg + 8) * 64 + ch2;
        h_out[i0] = h_in[i0] + o0;
        h_out[i1] = h_in[i1] + o1;
    }
}

// ================= readout =================
// old layout [n][o][ch] (fallback)
__global__ __launch_bounds__(256) void k_readout_part(
    const float* __restrict__ h, float* __restrict__ part16)
{
    __shared__ float part[4][64];
    const int t = threadIdx.x, b = blockIdx.x;
    const int c = t & 63, seg = t >> 6;
    float s = 0.f;
    const int r0 = b * 256 + seg * 64;
    for (int r = r0; r < r0 + 64; ++r) s += h[r * 64 + c];
    part[seg][c] = s;
    __syncthreads();
    if (t < 64) part16[b * 64 + t] = part[0][t] + part[1][t] + part[2][t] + part[3][t];
}

// h2 layout [n][ch][o] (fast)
__global__ __launch_bounds__(256) void k_readout_part2(
    const float* __restrict__ h, float* __restrict__ part16)
{
    const int t = threadIdx.x, b = blockIdx.x;
    const int ch = t >> 2, oq = t & 3;
    float s = 0.f;
#pragma unroll
    for (int nn = 0; nn < 16; ++nn) {
        const int n = b * 16 + nn;
        f32x4 v = *(const f32x4*)(h + n * 1024 + ch * 16 + oq * 4);
        s += (v[0] + v[1]) + (v[2] + v[3]);
    }
    s += __shfl_xor(s, 1);
    s += __shfl_xor(s, 2);
    if (oq == 0) part16[b * 64 + ch] = s;
}

__global__ __launch_bounds__(64) void k_readout_final(
    const float* __restrict__ part16, const float* __restrict__ rW, float* __restrict__ out)
{
    __shared__ float hbar[64];
    const int t = threadIdx.x;
    float s = 0.f;
#pragma unroll
    for (int b = 0; b < 16; ++b) s += part16[b * 64 + t];
    hbar[t] = s * (1.0f / 4096.0f);
    __syncthreads();
    if (t < 3) {
        float s2 = 0.f;
#pragma unroll
        for (int k = 0; k < 64; ++k) s2 += hbar[k] * rW[k * 3 + t];
        out[t] = s2;
    }
}

extern "C" void kernel_launch(void* const* d_in, const int* in_sizes, int n_in,
                              void* d_out, int out_size, void* d_ws, size_t ws_size,
                              hipStream_t stream)
{
    const float* pos      = (const float*)d_in[0];
    const float* x        = (const float*)d_in[1];
    const float* skb_W1   = (const float*)d_in[2];
    const float* skb_b1   = (const float*)d_in[3];
    const float* skb_W2   = (const float*)d_in[4];
    const float* skb_b2   = (const float*)d_in[5];
    const float* rkb_W1   = (const float*)d_in[6];
    const float* rkb_b1   = (const float*)d_in[7];
    const float* rkb_W2   = (const float*)d_in[8];
    const float* rkb_b2   = (const float*)d_in[9];
    const float* emb_W    = (const float*)d_in[10];
    const float* conv_sW  = (const float*)d_in[11];
    const float* conv_rW  = (const float*)d_in[12];
    const float* conv_b   = (const float*)d_in[13];
    const float* ln_scale = (const float*)d_in[14];
    const float* ln_bias  = (const float*)d_in[15];
    const float* lin1_W   = (const float*)d_in[16];
    const float* lin1_b   = (const float*)d_in[17];
    const float* lin2_W   = (const float*)d_in[18];
    const float* lin2_b   = (const float*)d_in[19];
    const float* readout_W= (const float*)d_in[20];
    float* out = (float*)d_out;

    unsigned char* ws = (unsigned char*)d_ws;
    float*  h_a    = (float*)(ws);                     // 1 MB
    float*  h_b    = (float*)(ws + 1048576);           // 1 MB
    float*  rkw    = (float*)(ws + 2097152);           // 128 KB
    __bf16* w1T    = (__bf16*)(ws + 2228224);          // 4 KB
    __bf16* w2T    = (__bf16*)(ws + 2232320);          // 4 KB
    __bf16* w2Tlo  = (__bf16*)(ws + 2236416);          // 4 KB
    __bf16* sWT    = (__bf16*)(ws + 2240512);          // 8 KB
    __bf16* sWTlo  = (__bf16*)(ws + 2248704);          // 8 KB
    float*  part16 = (float*)(ws + 2256896);           // 4 KB
    __bf16* kb_g   = (__bf16*)(ws + 2260992);          // 32 MB (single-copy kb)

    const bool fast = (ws_size >= 2260992ull + 33554432ull);

    if (fast) {
        k_setup<<<1041, 256, 0, stream>>>(x, emb_W, h_a,
                                          rkb_W1, rkb_b1, rkb_W2, rkb_b2, conv_rW, rkw,
                                          skb_W1, skb_W2, conv_sW,
                                          w1T, w2T, w2Tlo, sWT, sWTlo);
        k_kb2<<<1024, 256, 0, stream>>>(pos, skb_b1, skb_b2, w1T, w2T, w2Tlo, kb_g);
        k_conv7<<<256, 1024, 0, stream>>>(kb_g, sWT, sWTlo, conv_b, rkw,
                                          ln_scale, ln_bias, lin1_W, lin1_b,
                                          lin2_W, lin2_b, h_a, h_b, 0);
        k_conv7<<<256, 1024, 0, stream>>>(kb_g, sWT, sWTlo, conv_b, rkw,
                                          ln_scale, ln_bias, lin1_W, lin1_b,
                                          lin2_W, lin2_b, h_b, h_a, 1);
        k_readout_part2<<<16, 256, 0, stream>>>(h_a, part16);
        k_readout_final<<<1, 64, 0, stream>>>(part16, readout_W, out);
    } else {
        k_prep<<<1, 256, 0, stream>>>(skb_W1, skb_W2, conv_sW, w1T, w2T, w2Tlo, sWT, sWTlo);
        k_fiber2<<<16, 256, 0, stream>>>(rkb_W1, rkb_b1, rkb_W2, rkb_b2, conv_rW, rkw);
        k_init<<<1024, 256, 0, stream>>>(x, emb_W, h_a);
        k_layer2<<<256, 512, 0, stream>>>(pos, skb_b1, skb_b2, w1T, w2T, w2Tlo, sWT, sWTlo,
                                          conv_b, rkw, ln_scale, ln_bias, lin1_W, lin1_b,
                                          lin2_W, lin2_b, h_a, h_b, 0);
        k_layer2<<<256, 512, 0, stream>>>(pos, skb_b1, skb_b2, w1T, w2T, w2Tlo, sWT, sWTlo,
                                          conv_b, rkw, ln_scale, ln_bias, lin1_W, lin1_b,
                                          lin2_W, lin2_b, h_b, h_a, 1);
        k_readout_part<<<16, 256, 0, stream>>>(h_a, part16);
        k_readout_final<<<1, 64, 0, stream>>>(part16, readout_W, out);
    }
}

// Round 18
// 139.958 us; speedup vs baseline: 1.0057x; 1.0057x over previous
//
#include <hip/hip_runtime.h>
#include <math.h>

// PONITA fixed-size: B=1, N=256, NUM_ORI=16, H=64, BD=32, WF*H=256, L=2
#define NPTS 256
#define NORI 16
#define CH   64
#define BD   32
#define HID  64
#define STEP16 0.39269908169872414f

typedef __bf16 bf16x8 __attribute__((ext_vector_type(8)));
typedef float  f32x4  __attribute__((ext_vector_type(4)));

#define MFMA16(a, b, cc) __builtin_amdgcn_mfma_f32_16x16x32_bf16(a, b, cc, 0, 0, 0)

__device__ __forceinline__ float gelu_f(float x) {
    float x2 = x * x;
    float y2 = x * fmaf(0.07135481627f, x2, 1.5957691216f);   // 2y
    float e = __expf(y2);
    return x - x * __builtin_amdgcn_rcpf(e + 1.0f);           // x*(1 - 1/(e+1))
}

__device__ __forceinline__ unsigned pk2(float x, float y) {
    union { __bf16 h[2]; unsigned u; } r;
    r.h[0] = (__bf16)x; r.h[1] = (__bf16)y;
    return r.u;
}

// ================= device helpers =================
__device__ __forceinline__ void dev_prep(
    const float* __restrict__ skb_W1, const float* __restrict__ skb_W2,
    const float* __restrict__ conv_sW,
    __bf16* __restrict__ w1T, __bf16* __restrict__ w2T, __bf16* __restrict__ w2Tlo,
    __bf16* __restrict__ sWT, __bf16* __restrict__ sWTlo, int t)
{
    if (t < 64) {
        float f[9];
        f[0] = skb_W1[t];
        f[1] = skb_W1[64 + t];
        f[2] = skb_W1[128 + t];
        f[3] = skb_W1[192 + t] + skb_W1[256 + t];
        f[4] = skb_W1[320 + t];
        f[5] = skb_W1[384 + t];
        f[6] = skb_W1[448 + t] + skb_W1[512 + t] + skb_W1[640 + t];
        f[7] = skb_W1[576 + t] + skb_W1[704 + t] + skb_W1[768 + t];
        f[8] = skb_W1[832 + t];
#pragma unroll
        for (int k = 0; k < 9; ++k) {
            __bf16 hi = (__bf16)f[k];
            w1T[t * 32 + k]      = hi;
            w1T[t * 32 + 9 + k]  = (__bf16)(f[k] - (float)hi);
            w1T[t * 32 + 18 + k] = hi;
        }
#pragma unroll
        for (int k = 27; k < 32; ++k) w1T[t * 32 + k] = (__bf16)0.0f;
    }
    for (int i = t; i < 2048; i += 256) {
        int n = i >> 6, kk = i & 63;
        float v = skb_W2[kk * 32 + n];
        __bf16 hi = (__bf16)v;
        w2T[i]   = hi;
        w2Tlo[i] = (__bf16)(v - (float)hi);
    }
    for (int i = t; i < 4096; i += 256) {
        int ll = i >> 11, chh = (i >> 5) & 63, k = i & 31;
        float v = conv_sW[(ll * 32 + k) * 64 + chh];
        __bf16 hi = (__bf16)v;
        sWT[i]   = hi;
        sWTlo[i] = (__bf16)(v - (float)hi);
    }
}

__device__ __forceinline__ void dev_fiber(
    const float* __restrict__ rkb_W1, const float* __restrict__ rkb_b1,
    const float* __restrict__ rkb_W2, const float* __restrict__ rkb_b2,
    const float* __restrict__ conv_rW, float* __restrict__ rk, int p, int t)
{
    __shared__ float w1L[3 * 64], b1L[64], w2L[64 * 32], b2L[32];
    __shared__ float rwL[2 * 32 * 64];
    __shared__ float t1L[16 * 64];
    __shared__ float fbL[16 * 32];

    if (t < 192) w1L[t] = rkb_W1[t];
    if (t >= 192 && t < 256) b1L[t - 192] = rkb_b1[t - 192];
    for (int i = t; i < 2048; i += 256) w2L[i] = rkb_W2[i];
    if (t < 32) b2L[t] = rkb_b2[t];
    for (int i = t; i < 4096; i += 256) rwL[i] = conv_rW[i];
    __syncthreads();

    const int o = t & 15;
    const float cp = cosf(p * STEP16), sp = sinf(p * STEP16);
    const float co = cosf(o * STEP16), so = sinf(o * STEP16);
    const float s0 = cp * co + sp * so;
    const float m1 = s0 * s0, m2 = m1 * s0;

    {
        const int jg = t >> 4;
#pragma unroll
        for (int u = 0; u < 4; ++u) {
            const int j = jg * 4 + u;
            float a = b1L[j] + s0 * w1L[j] + m1 * w1L[64 + j] + m2 * w1L[128 + j];
            t1L[o * 64 + j] = gelu_f(a);
        }
    }
    __syncthreads();
    {
        const int kg = t >> 4;
#pragma unroll
        for (int kk = 0; kk < 2; ++kk) {
            const int k = kg + kk * 16;
            float a = b2L[k];
#pragma unroll
            for (int j = 0; j < 64; ++j) a += t1L[o * 64 + j] * w2L[j * 32 + k];
            fbL[o * 32 + k] = gelu_f(a);
        }
    }
    __syncthreads();
    {
        const int o2 = t >> 4;
        const int chg = (t & 15) * 4;
#pragma unroll
        for (int l = 0; l < 2; ++l) {
            f32x4 acc = {0.f, 0.f, 0.f, 0.f};
#pragma unroll
            for (int k = 0; k < 32; ++k) {
                const float fv = fbL[o2 * 32 + k];
                const f32x4 rv = *(const f32x4*)(rwL + (l * 32 + k) * 64 + chg);
                acc[0] = fmaf(fv, rv[0], acc[0]);
                acc[1] = fmaf(fv, rv[1], acc[1]);
                acc[2] = fmaf(fv, rv[2], acc[2]);
                acc[3] = fmaf(fv, rv[3], acc[3]);
            }
            *(f32x4*)(rk + (l * 256 + p * 16 + o2) * 64 + chg) = acc;
        }
    }
}

// ================= standalone small kernels =================
__global__ __launch_bounds__(256) void k_prep(
    const float* __restrict__ skb_W1, const float* __restrict__ skb_W2,
    const float* __restrict__ conv_sW,
    __bf16* __restrict__ w1T, __bf16* __restrict__ w2T, __bf16* __restrict__ w2Tlo,
    __bf16* __restrict__ sWT, __bf16* __restrict__ sWTlo)
{
    dev_prep(skb_W1, skb_W2, conv_sW, w1T, w2T, w2Tlo, sWT, sWTlo, threadIdx.x);
}

__global__ __launch_bounds__(256) void k_fiber2(
    const float* __restrict__ rkb_W1, const float* __restrict__ rkb_b1,
    const float* __restrict__ rkb_W2, const float* __restrict__ rkb_b2,
    const float* __restrict__ conv_rW, float* __restrict__ rk)
{
    dev_fiber(rkb_W1, rkb_b1, rkb_W2, rkb_b2, conv_rW, rk, blockIdx.x, threadIdx.x);
}

// old-layout h init (fallback path): h[n][o][ch]
__global__ __launch_bounds__(256) void k_init(
    const float* __restrict__ x, const float* __restrict__ emb_W, float* __restrict__ h)
{
    int idx = blockIdx.x * 256 + threadIdx.x;
    int ch = idx & 63;
    int n  = idx >> 10;
    h[idx] = x[n * 3] * emb_W[ch] + x[n * 3 + 1] * emb_W[64 + ch] + x[n * 3 + 2] * emb_W[128 + ch];
}

// fused setup (fast path): blocks [0,1024) init h2[n][ch][o]; [1024,1040) fiber; 1040 prep
__global__ __launch_bounds__(256) void k_setup(
    const float* __restrict__ x, const float* __restrict__ emb_W, float* __restrict__ h2,
    const float* __restrict__ rkb_W1, const float* __restrict__ rkb_b1,
    const float* __restrict__ rkb_W2, const float* __restrict__ rkb_b2,
    const float* __restrict__ conv_rW, float* __restrict__ rk,
    const float* __restrict__ skb_W1, const float* __restrict__ skb_W2,
    const float* __restrict__ conv_sW,
    __bf16* __restrict__ w1T, __bf16* __restrict__ w2T, __bf16* __restrict__ w2Tlo,
    __bf16* __restrict__ sWT, __bf16* __restrict__ sWTlo)
{
    const int b = blockIdx.x, t = threadIdx.x;
    if (b < 1024) {
        int idx = b * 256 + t;                  // (n*64+ch)*16 + o
        int ch = (idx >> 4) & 63;
        int n  = idx >> 10;
        h2[idx] = x[n * 3] * emb_W[ch] + x[n * 3 + 1] * emb_W[64 + ch]
                + x[n * 3 + 2] * emb_W[128 + ch];
    } else if (b < 1040) {
        dev_fiber(rkb_W1, rkb_b1, rkb_W2, rkb_b2, conv_rW, rk, b - 1024, t);
    } else {
        dev_prep(skb_W1, skb_W2, conv_sW, w1T, w2T, w2Tlo, sWT, sWTlo, t);
    }
}

// ================= kb materialization: single copy, grid 2048 for occupancy ==========
// kb(m,n,o) == kb(n,m,o^8) exactly. Canonical o<8 copy only: kb_g[(m*256+n)*8+o]
// (64B rows, chunk-swizzled by o&3). Block = (pair, ohalf, mhalf, mi2) -> 1 m, 4 oi.
__global__ __launch_bounds__(256) void k_kb2(
    const float* __restrict__ pos,
    const float* __restrict__ skb_b1, const float* __restrict__ skb_b2,
    const __bf16* __restrict__ w1T, const __bf16* __restrict__ w2T,
    const __bf16* __restrict__ w2Tlo, __bf16* __restrict__ kb_g)
{
    const int t = threadIdx.x;
    const int c = t & 15, qq = (t >> 4) & 3, w = t >> 6;
    const int b = blockIdx.x;
    const int pair = b >> 3;
    const int ohalf = (b >> 2) & 1;
    const int mhalf = (b >> 1) & 1;
    const int mi2   = b & 1;
    const int m0 = (pair >> 4) * 16, n0 = (pair & 15) * 16;

    bf16x8 w1B[4], w2A[2][2], w2Alo[2][2];
    float b1x[4][4], b2x[2][4];
#pragma unroll
    for (int ni = 0; ni < 4; ++ni) {
        w1B[ni] = *(const bf16x8*)(w1T + (ni * 16 + c) * 32 + qq * 8);
#pragma unroll
        for (int r = 0; r < 4; ++r) b1x[ni][r] = skb_b1[ni * 16 + qq * 4 + r];
    }
#pragma unroll
    for (int mk = 0; mk < 2; ++mk) {
#pragma unroll
        for (int ks = 0; ks < 2; ++ks) {
            w2A[mk][ks]   = *(const bf16x8*)(w2T   + (mk * 16 + c) * 64 + ks * 32 + qq * 8);
            w2Alo[mk][ks] = *(const bf16x8*)(w2Tlo + (mk * 16 + c) * 64 + ks * 32 + qq * 8);
        }
#pragma unroll
        for (int r = 0; r < 4; ++r) b2x[mk][r] = skb_b2[mk * 16 + qq * 4 + r];
    }

    const int n = n0 + c;
    const float pnx = pos[2 * n], pny = pos[2 * n + 1];
    float cosv[4], sinv[4];
#pragma unroll
    for (int oi = 0; oi < 4; ++oi) {
        float th = (float)(ohalf * 4 + oi) * STEP16;
        cosv[oi] = cosf(th); sinv[oi] = sinf(th);
    }
    const int s0lane = c + ((qq & 1) << 5);
    const int s1lane = s0lane + 16;
    const int selhi = qq >> 1;
    const f32x4 zf = {0.f, 0.f, 0.f, 0.f};

    const int m = m0 + w * 4 + mhalf * 2 + mi2;
    const float dx = pnx - pos[2 * m];
    const float dy = pny - pos[2 * m + 1];
#pragma unroll
    for (int oi = 0; oi < 4; ++oi) {
        const int o = ohalf * 4 + oi;
        float a = dx * cosv[oi] + dy * sinv[oi];
        float vx = dx - dx * a, vy = dy - dy * a;
        float b2 = sqrtf(vx * vx + vy * vy);
        float mfv[9];
        mfv[0] = a; mfv[1] = b2; mfv[2] = a * a; mfv[3] = a * b2; mfv[4] = b2 * b2;
        mfv[5] = mfv[2] * a; mfv[6] = mfv[2] * b2; mfv[7] = mfv[3] * b2; mfv[8] = mfv[4] * b2;
        __bf16 mh[9], ml[9];
#pragma unroll
        for (int i = 0; i < 9; ++i) {
            mh[i] = (__bf16)mfv[i];
            ml[i] = (__bf16)(mfv[i] - (float)mh[i]);
        }
        bf16x8 mb;
        if (qq == 0) {
            mb[0]=mh[0]; mb[1]=mh[1]; mb[2]=mh[2]; mb[3]=mh[3];
            mb[4]=mh[4]; mb[5]=mh[5]; mb[6]=mh[6]; mb[7]=mh[7];
        } else if (qq == 1) {
            mb[0]=mh[8]; mb[1]=mh[0]; mb[2]=mh[1]; mb[3]=mh[2];
            mb[4]=mh[3]; mb[5]=mh[4]; mb[6]=mh[5]; mb[7]=mh[6];
        } else if (qq == 2) {
            mb[0]=mh[7]; mb[1]=mh[8]; mb[2]=ml[0]; mb[3]=ml[1];
            mb[4]=ml[2]; mb[5]=ml[3]; mb[6]=ml[4]; mb[7]=ml[5];
        } else {
            mb[0]=ml[6]; mb[1]=ml[7]; mb[2]=ml[8]; mb[3]=(__bf16)0.0f;
            mb[4]=(__bf16)0.0f; mb[5]=(__bf16)0.0f; mb[6]=(__bf16)0.0f; mb[7]=(__bf16)0.0f;
        }

        unsigned t1p[4][2];
#pragma unroll
        for (int ni = 0; ni < 4; ++ni) {
            f32x4 acc = MFMA16(w1B[ni], mb, zf);
            float g0 = gelu_f(acc[0] + b1x[ni][0]);
            float g1 = gelu_f(acc[1] + b1x[ni][1]);
            float g2 = gelu_f(acc[2] + b1x[ni][2]);
            float g3 = gelu_f(acc[3] + b1x[ni][3]);
            t1p[ni][0] = pk2(g0, g1);
            t1p[ni][1] = pk2(g2, g3);
        }

        bf16x8 B2[2];
#pragma unroll
        for (int ks = 0; ks < 2; ++ks) {
            const unsigned lo0 = t1p[ks * 2][0],     lo1 = t1p[ks * 2][1];
            const unsigned hi0 = t1p[ks * 2 + 1][0], hi1 = t1p[ks * 2 + 1][1];
            unsigned aL0 = (unsigned)__shfl((int)lo0, s0lane);
            unsigned aL1 = (unsigned)__shfl((int)lo1, s0lane);
            unsigned aL2 = (unsigned)__shfl((int)lo0, s1lane);
            unsigned aL3 = (unsigned)__shfl((int)lo1, s1lane);
            unsigned aH0 = (unsigned)__shfl((int)hi0, s0lane);
            unsigned aH1 = (unsigned)__shfl((int)hi1, s0lane);
            unsigned aH2 = (unsigned)__shfl((int)hi0, s1lane);
            unsigned aH3 = (unsigned)__shfl((int)hi1, s1lane);
            union { unsigned u[4]; bf16x8 v; } bu;
            bu.u[0] = selhi ? aH0 : aL0;
            bu.u[1] = selhi ? aH1 : aL1;
            bu.u[2] = selhi ? aH2 : aL2;
            bu.u[3] = selhi ? aH3 : aL3;
            B2[ks] = bu.v;
        }

        const size_t ptP = (size_t)(m * 256 + n) * 8 + o;   // canonical copy only
        const int swz = o & 3;
#pragma unroll
        for (int mk = 0; mk < 2; ++mk) {
            f32x4 acc = MFMA16(w2A[mk][0], B2[0], zf);
            acc = MFMA16(w2A[mk][1], B2[1], acc);
            acc = MFMA16(w2Alo[mk][0], B2[0], acc);
            acc = MFMA16(w2Alo[mk][1], B2[1], acc);
            float g0 = gelu_f(acc[0] + b2x[mk][0]);
            float g1 = gelu_f(acc[1] + b2x[mk][1]);
            float g2 = gelu_f(acc[2] + b2x[mk][2]);
            float g3 = gelu_f(acc[3] + b2x[mk][3]);
            uint2 pv; pv.x = pk2(g0, g1); pv.y = pk2(g2, g3);
            const int off = (((mk * 2 + (qq >> 1)) ^ swz) << 4) + ((qq & 1) << 3);
            *(uint2*)((char*)kb_g + ptP * 64 + off) = pv;
        }
    }
}

// ================= conv layer v8: depth-3 register pipeline, pins on BOTH sides ==========
// Groups [kb(1)+h(4)] issued 3 tiles ahead; sched_barrier(0) after EVERY issue cluster
// AND every wait (no un-fenced window for the scheduler to sink loads). Mirror-read
// half-size kb (conv7 addressing). h layout [n][ch][o] (h2). LDS only in epilogue.
__global__ __launch_bounds__(1024) void k_conv8(
    const __bf16* __restrict__ kb_g,
    const __bf16* __restrict__ sWT, const __bf16* __restrict__ sWTlo,
    const float* __restrict__ conv_b, const float* __restrict__ rkg,
    const float* __restrict__ ln_scale, const float* __restrict__ ln_bias,
    const float* __restrict__ lin1_W, const float* __restrict__ lin1_b,
    const float* __restrict__ lin2_W, const float* __restrict__ lin2_b,
    const float* __restrict__ h_in, float* __restrict__ h_out, int l)
{
    __shared__ __align__(16) unsigned char smem[90112];
    const int t = threadIdx.x;
    const int m = blockIdx.x;
    const int w = t >> 6, lane = t & 63;
    const int qq = lane >> 4, c = lane & 15;
    const f32x4 zf = {0.f, 0.f, 0.f, 0.f};

    bf16x8 sWB[4], sWBlo[4];
#pragma unroll
    for (int ni = 0; ni < 4; ++ni) {
        sWB[ni]   = *(const bf16x8*)(sWT   + l * 2048 + (ni * 16 + c) * 32 + qq * 8);
        sWBlo[ni] = *(const bf16x8*)(sWTlo + l * 2048 + (ni * 16 + c) * 32 + qq * 8);
    }

    f32x4 cacc[4];
#pragma unroll
    for (int ni = 0; ni < 4; ++ni)
#pragma unroll
        for (int r = 0; r < 4; ++r) cacc[ni][r] = 0.f;

    size_t lp, tsb;
    if (c < 8) { lp = (size_t)m * 2048 + (size_t)w * 8 + c;          tsb = 128ull * 64; }
    else       { lp = (size_t)w * 2048 + (size_t)m * 8 + (c - 8);    tsb = 32768ull * 64; }
    const char* kbsrc = (const char*)kb_g + lp * 64 + ((qq ^ (c & 3)) << 4);
    const float* hbase = h_in + c * 16 + qq * 4;   // + n*1024 + ni*256

    // ---- prologue: issue groups 0,1,2 (5 loads each); pin with sched_barrier ----
    bf16x8 kbf[3];
    f32x4 hbf[3][4];
#pragma unroll
    for (int g0 = 0; g0 < 3; ++g0) {
        kbf[g0] = *(const bf16x8*)(kbsrc + (size_t)g0 * tsb);
        const float* hp = hbase + (g0 * 16 + w) * 1024;
        hbf[g0][0] = *(const f32x4*)(hp);
        hbf[g0][1] = *(const f32x4*)(hp + 256);
        hbf[g0][2] = *(const f32x4*)(hp + 512);
        hbf[g0][3] = *(const f32x4*)(hp + 768);
        __builtin_amdgcn_sched_barrier(0);
    }

#pragma unroll
    for (int tile = 0; tile < 16; ++tile) {
        const int bi = tile % 3;
        // outstanding groups before wait: t..min(15,t+2); keep 2 groups (10 loads)
        if (tile <= 13)      { asm volatile("s_waitcnt vmcnt(10)" ::: "memory"); }
        else if (tile == 14) { asm volatile("s_waitcnt vmcnt(5)"  ::: "memory"); }
        else                 { asm volatile("s_waitcnt vmcnt(0)"  ::: "memory"); }
        __builtin_amdgcn_sched_barrier(0);

        const bf16x8 aF = kbf[bi];
        f32x4 g;
#pragma unroll
        for (int ni = 0; ni < 4; ++ni) {
            g = MFMA16(aF, sWB[ni], zf);
            g = MFMA16(aF, sWBlo[ni], g);
#pragma unroll
            for (int r = 0; r < 4; ++r)
                cacc[ni][r] = fmaf(g[r], hbf[bi][ni][r], cacc[ni][r]);
        }
        __builtin_amdgcn_sched_barrier(0);

        // issue group(t+3) into the buffer just consumed; pin immediately after
        if (tile <= 12) {
            kbf[bi] = *(const bf16x8*)(kbsrc + (size_t)(tile + 3) * tsb);
            const float* hp = hbase + ((tile + 3) * 16 + w) * 1024;
            hbf[bi][0] = *(const f32x4*)(hp);
            hbf[bi][1] = *(const f32x4*)(hp + 256);
            hbf[bi][2] = *(const f32x4*)(hp + 512);
            hbf[bi][3] = *(const f32x4*)(hp + 768);
            __builtin_amdgcn_sched_barrier(0);
        }
    }
    __syncthreads();

    // ---- partial c1 per wave -> LDS ----
    {
        float* c1p = (float*)smem;
#pragma unroll
        for (int ni = 0; ni < 4; ++ni)
#pragma unroll
            for (int r = 0; r < 4; ++r)
                c1p[w * 1024 + (qq * 4 + r) * 64 + ni * 16 + c] = cacc[ni][r];
    }
    __syncthreads();
    {
        float* c1p = (float*)smem;
        float* c1r = (float*)(smem + 65536);
        float s = 0.f;
#pragma unroll
        for (int ww = 0; ww < 16; ++ww) s += c1p[ww * 1024 + t];
        c1r[t] = s;
    }
    __syncthreads();

    // ---- orientation mixing + bias + LayerNorm (wave w = p, lane = ch) ----
    {
        float* c1r = (float*)(smem + 65536);
        float* cns = (float*)(smem + 69632);
        const int ch = lane;
        const float cb  = conv_b[l * 64 + ch];
        const float lsc = ln_scale[l * 64 + ch], lbi = ln_bias[l * 64 + ch];
        const float* rkp = rkg + (l * 256 + w * 16) * 64 + ch;
        float s = cb;
#pragma unroll
        for (int o = 0; o < 16; ++o) s += c1r[o * 64 + ch] * rkp[o * 64];
        float red = s;
#pragma unroll
        for (int off = 32; off > 0; off >>= 1) red += __shfl_xor(red, off);
        float mu = red * (1.0f / 64.0f);
        float d = s - mu;
        float r2 = d * d;
#pragma unroll
        for (int off = 32; off > 0; off >>= 1) r2 += __shfl_xor(r2, off);
        cns[w * 64 + ch] = d * rsqrtf(r2 * (1.0f / 64.0f) + 1e-6f) * lsc + lbi;
    }
    __syncthreads();

    // ---- lin1 ----
    {
        float* cns = (float*)(smem + 69632);
        float* usS = (float*)(smem + 73728);
        const int j = t & 255, q4 = t >> 8;
        const float* W1l = lin1_W + l * 64 * 256;
        const float bl1 = lin1_b[l * 256 + j];
        float ua[4];
#pragma unroll
        for (int pi = 0; pi < 4; ++pi) ua[pi] = bl1;
#pragma unroll 4
        for (int c2 = 0; c2 < 64; ++c2) {
            const float wv = W1l[c2 * 256 + j];
#pragma unroll
            for (int pi = 0; pi < 4; ++pi)
                ua[pi] = fmaf(cns[(q4 * 4 + pi) * 64 + c2], wv, ua[pi]);
        }
#pragma unroll
        for (int pi = 0; pi < 4; ++pi) usS[(q4 * 4 + pi) * 256 + j] = gelu_f(ua[pi]);
    }
    __syncthreads();

    // ---- lin2 + residual (h2 layout [n][ch][o]) ----
    {
        float* usS = (float*)(smem + 73728);
        const int ch2 = t & 63, pg = t >> 6;
        const float* W2l = lin2_W + l * 256 * 64;
        float o0 = lin2_b[l * 64 + ch2];
#pragma unroll 4
        for (int j = 0; j < 256; ++j)
            o0 = fmaf(usS[pg * 256 + j], W2l[j * 64 + ch2], o0);
        const int i0 = m * 1024 + ch2 * 16 + pg;
        h_out[i0] = h_in[i0] + o0;
    }
}

// ================= fallback conv layer (old layout), verbatim from passing round ========
__global__ __launch_bounds__(512, 1) void k_layer2(
    const float* __restrict__ pos,
    const float* __restrict__ skb_b1, const float* __restrict__ skb_b2,
    const __bf16* __restrict__ w1T, const __bf16* __restrict__ w2T,
    const __bf16* __restrict__ w2Tlo,
    const __bf16* __restrict__ sWT, const __bf16* __restrict__ sWTlo,
    const float* __restrict__ conv_b, const float* __restrict__ rkg,
    const float* __restrict__ ln_scale, const float* __restrict__ ln_bias,
    const float* __restrict__ lin1_W, const float* __restrict__ lin1_b,
    const float* __restrict__ lin2_W, const float* __restrict__ lin2_b,
    const float* __restrict__ h_in, float* __restrict__ h_out, int l)
{
    __shared__ __align__(16) unsigned char smem[57344];
    const int t = threadIdx.x;
    const int m = blockIdx.x;
    const int w = t >> 6, lane = t & 63;
    const int qq = lane >> 4, c = lane & 15;

    bf16x8 w1B[4], sWB[4], sWBlo[4], w2B[2][2], w2Blo[2][2];
    float b1v[4], b2v[2];
#pragma unroll
    for (int ni = 0; ni < 4; ++ni) {
        w1B[ni]   = *(const bf16x8*)(w1T + (ni * 16 + c) * 32 + qq * 8);
        sWB[ni]   = *(const bf16x8*)(sWT   + l * 2048 + (ni * 16 + c) * 32 + qq * 8);
        sWBlo[ni] = *(const bf16x8*)(sWTlo + l * 2048 + (ni * 16 + c) * 32 + qq * 8);
        b1v[ni] = skb_b1[ni * 16 + c];
    }
#pragma unroll
    for (int nt = 0; nt < 2; ++nt) {
        b2v[nt] = skb_b2[nt * 16 + c];
#pragma unroll
        for (int ks = 0; ks < 2; ++ks) {
            w2B[nt][ks]   = *(const bf16x8*)(w2T   + (nt * 16 + c) * 64 + ks * 32 + qq * 8);
            w2Blo[nt][ks] = *(const bf16x8*)(w2Tlo + (nt * 16 + c) * 64 + ks * 32 + qq * 8);
        }
    }

    const float pmx = pos[2 * m], pmy = pos[2 * m + 1];
    float co_ = 0.f, so_ = 0.f;
    if (t < 256) { float th = (float)(t & 15) * STEP16; co_ = cosf(th); so_ = sinf(th); }

    f32x4 cacc[4];
#pragma unroll
    for (int ni = 0; ni < 4; ++ni)
#pragma unroll
        for (int r = 0; r < 4; ++r) cacc[ni][r] = 0.f;

#pragma unroll 1
    for (int tile = 0; tile < 16; ++tile) {
        if (t < 256) {
            const int n = tile * 16 + (t >> 4);
            float dx = pos[2 * n] - pmx, dy = pos[2 * n + 1] - pmy;
            float a = dx * co_ + dy * so_;
            float vx = dx - dx * a, vy = dy - dy * a;
            float b = sqrtf(vx * vx + vy * vy);
            float mf[9];
            mf[0] = a; mf[1] = b; mf[2] = a * a; mf[3] = a * b; mf[4] = b * b;
            mf[5] = mf[2] * a; mf[6] = mf[2] * b; mf[7] = mf[3] * b; mf[8] = mf[4] * b;
            __bf16 s[32];
#pragma unroll
            for (int i = 0; i < 9; ++i) {
                __bf16 hi = (__bf16)mf[i];
                s[i] = hi; s[9 + i] = hi;
                s[18 + i] = (__bf16)(mf[i] - (float)hi);
            }
#pragma unroll
            for (int i = 27; i < 32; ++i) s[i] = (__bf16)0.0f;
            unsigned char* rowp = smem + t * 64;
#pragma unroll
            for (int u = 0; u < 4; ++u) {
                bf16x8 vv;
#pragma unroll
                for (int j = 0; j < 8; ++j) vv[j] = s[u * 8 + j];
                *(bf16x8*)(rowp + ((u ^ (t & 3)) << 4)) = vv;
            }
        }
        __syncthreads();

#pragma unroll
        for (int mm = 0; mm < 2; ++mm) {
            const int row = (2 * w + mm) * 16 + c;
            bf16x8 aF = *(const bf16x8*)(smem + row * 64 + ((qq ^ (row & 3)) << 4));
#pragma unroll
            for (int ni = 0; ni < 4; ++ni) {
                f32x4 acc = {0.f, 0.f, 0.f, 0.f};
                acc = MFMA16(aF, w1B[ni], acc);
#pragma unroll
                for (int r = 0; r < 4; ++r) {
                    const int ro = (2 * w + mm) * 16 + qq * 4 + r;
                    float g = gelu_f(acc[r] + b1v[ni]);
                    const int chc = ni * 16 + c;
                    *(__bf16*)(smem + 16384 + ro * 128 + (((chc >> 3) ^ (ro & 7)) << 4)
                               + ((chc & 7) << 1)) = (__bf16)g;
                }
            }
        }
        __syncthreads();

#pragma unroll
        for (int mm = 0; mm < 2; ++mm) {
            const int row = (2 * w + mm) * 16 + c;
            bf16x8 a0 = *(const bf16x8*)(smem + 16384 + row * 128 + ((qq ^ (row & 7)) << 4));
            bf16x8 a1 = *(const bf16x8*)(smem + 16384 + row * 128 + (((4 + qq) ^ (row & 7)) << 4));
#pragma unroll
            for (int nt = 0; nt < 2; ++nt) {
                f32x4 acc = {0.f, 0.f, 0.f, 0.f};
                acc = MFMA16(a0, w2B[nt][0], acc);
                acc = MFMA16(a1, w2B[nt][1], acc);
                acc = MFMA16(a0, w2Blo[nt][0], acc);
                acc = MFMA16(a1, w2Blo[nt][1], acc);
#pragma unroll
                for (int r = 0; r < 4; ++r) {
                    const int ro = (2 * w + mm) * 16 + qq * 4 + r;
                    float g = gelu_f(acc[r] + b2v[nt]);
                    const int kc = nt * 16 + c;
                    *(__bf16*)(smem + ro * 64 + (((kc >> 3) ^ (ro & 3)) << 4)
                               + ((kc & 7) << 1)) = (__bf16)g;
                }
            }
        }
        __syncthreads();

#pragma unroll
        for (int mm = 0; mm < 2; ++mm) {
            const int mi = 2 * w + mm;
            const int row = mi * 16 + c;
            bf16x8 aF = *(const bf16x8*)(smem + row * 64 + ((qq ^ (row & 3)) << 4));
            const int nbase = (tile * 16 + mi) * 1024 + qq * 256;
#pragma unroll
            for (int ni = 0; ni < 4; ++ni) {
                f32x4 g3 = {0.f, 0.f, 0.f, 0.f};
                g3 = MFMA16(aF, sWB[ni], g3);
                g3 = MFMA16(aF, sWBlo[ni], g3);
#pragma unroll
                for (int r = 0; r < 4; ++r) {
                    float hv = h_in[nbase + r * 64 + ni * 16 + c];
                    cacc[ni][r] = fmaf(g3[r], hv, cacc[ni][r]);
                }
            }
        }
        __syncthreads();
    }

    {
        float* c1p = (float*)smem;
#pragma unroll
        for (int ni = 0; ni < 4; ++ni)
#pragma unroll
            for (int r = 0; r < 4; ++r)
                c1p[w * 1024 + (qq * 4 + r) * 64 + ni * 16 + c] = cacc[ni][r];
    }
    __syncthreads();
    {
        float* c1p = (float*)smem;
        float* c1r = (float*)(smem + 32768);
        for (int i = t; i < 1024; i += 512) {
            float s = 0.f;
#pragma unroll
            for (int ww = 0; ww < 8; ++ww) s += c1p[ww * 1024 + i];
            c1r[i] = s;
        }
    }
    __syncthreads();

    {
        float* c1r = (float*)(smem + 32768);
        float* cns = (float*)(smem + 36864);
        const int ch = lane;
        const float cb  = conv_b[l * 64 + ch];
        const float lsc = ln_scale[l * 64 + ch], lbi = ln_bias[l * 64 + ch];
#pragma unroll
        for (int pp = 0; pp < 2; ++pp) {
            const int p = w + pp * 8;
            const float* rkp = rkg + (l * 256 + p * 16) * 64 + ch;
            float s = cb;
#pragma unroll
            for (int o = 0; o < 16; ++o) s += c1r[o * 64 + ch] * rkp[o * 64];
            float red = s;
#pragma unroll
            for (int off = 32; off > 0; off >>= 1) red += __shfl_xor(red, off);
            float mu = red * (1.0f / 64.0f);
            float d = s - mu;
            float r2 = d * d;
#pragma unroll
            for (int off = 32; off > 0; off >>= 1) r2 += __shfl_xor(r2, off);
            cns[p * 64 + ch] = d * rsqrtf(r2 * (1.0f / 64.0f) + 1e-6f) * lsc + lbi;
        }
    }
    __syncthreads();

    {
        float* cns = (float*)(smem + 36864);
        float* usS = (float*)(smem + 40960);
        const int j = t & 255, half = t >> 8;
        const float* W1l = lin1_W + l * 64 * 256;
        const float bl1 = lin1_b[l * 256 + j];
        float ua[8];
#pragma unroll
        for (int pi = 0; pi < 8; ++pi) ua[pi] = bl1;
#pragma unroll 1
        for (int c2 = 0; c2 < 64; ++c2) {
            const float wv = W1l[c2 * 256 + j];
#pragma unroll
            for (int pi = 0; pi < 8; ++pi)
                ua[pi] = fmaf(cns[(half * 8 + pi) * 64 + c2], wv, ua[pi]);
        }
#pragma unroll
        for (int pi = 0; pi < 8; ++pi) usS[(half * 8 + pi) * 256 + j] = gelu_f(ua[pi]);
    }
    __syncthreads();

    {
        float* usS = (float*)(smem + 40960);
        const int ch2 = t & 63, pg = t >> 6;
        const float* W2l = lin2_W + l * 256 * 64;
        const float bl2 = lin2_b[l * 64 + ch2];
        float o0 = bl2, o1 = bl2;
#pragma unroll 2
        for (int j = 0; j < 256; ++j) {
            const float wv = W2l[j * 64 + ch2];
            o0 = fmaf(usS[pg * 256 + j], wv, o0);
            o1 = fmaf(usS[(pg + 8) * 256 + j], wv, o1);
        }
        const int i0 = (m * 16 + pg) * 64 + ch2;
        const int i1 = (m * 16 + pg + 8) * 64 + ch2;
        h_out[i0] = h_in[i0] + o0;
        h_out[i1] = h_in[i1] + o1;
    }
}

// ================= readout =================
__global__ __launch_bounds__(256) void k_readout_part(
    const float* __restrict__ h, float* __restrict__ part16)
{
    __shared__ float part[4][64];
    const int t = threadIdx.x, b = blockIdx.x;
    const int c = t & 63, seg = t >> 6;
    float s = 0.f;
    const int r0 = b * 256 + seg * 64;
    for (int r = r0; r < r0 + 64; ++r) s += h[r * 64 + c];
    part[seg][c] = s;
    __syncthreads();
    if (t < 64) part16[b * 64 + t] = part[0][t] + part[1][t] + part[2][t] + part[3][t];
}

__global__ __launch_bounds__(256) void k_readout_part2(
    const float* __restrict__ h, float* __restrict__ part16)
{
    const int t = threadIdx.x, b = blockIdx.x;
    const int ch = t >> 2, oq = t & 3;
    float s = 0.f;
#pragma unroll
    for (int nn = 0; nn < 16; ++nn) {
        const int n = b * 16 + nn;
        f32x4 v = *(const f32x4*)(h + n * 1024 + ch * 16 + oq * 4);
        s += (v[0] + v[1]) + (v[2] + v[3]);
    }
    s += __shfl_xor(s, 1);
    s += __shfl_xor(s, 2);
    if (oq == 0) part16[b * 64 + ch] = s;
}

__global__ __launch_bounds__(64) void k_readout_final(
    const float* __restrict__ part16, const float* __restrict__ rW, float* __restrict__ out)
{
    __shared__ float hbar[64];
    const int t = threadIdx.x;
    float s = 0.f;
#pragma unroll
    for (int b = 0; b < 16; ++b) s += part16[b * 64 + t];
    hbar[t] = s * (1.0f / 4096.0f);
    __syncthreads();
    if (t < 3) {
        float s2 = 0.f;
#pragma unroll
        for (int k = 0; k < 64; ++k) s2 += hbar[k] * rW[k * 3 + t];
        out[t] = s2;
    }
}

extern "C" void kernel_launch(void* const* d_in, const int* in_sizes, int n_in,
                              void* d_out, int out_size, void* d_ws, size_t ws_size,
                              hipStream_t stream)
{
    const float* pos      = (const float*)d_in[0];
    const float* x        = (const float*)d_in[1];
    const float* skb_W1   = (const float*)d_in[2];
    const float* skb_b1   = (const float*)d_in[3];
    const float* skb_W2   = (const float*)d_in[4];
    const float* skb_b2   = (const float*)d_in[5];
    const float* rkb_W1   = (const float*)d_in[6];
    const float* rkb_b1   = (const float*)d_in[7];
    const float* rkb_W2   = (const float*)d_in[8];
    const float* rkb_b2   = (const float*)d_in[9];
    const float* emb_W    = (const float*)d_in[10];
    const float* conv_sW  = (const float*)d_in[11];
    const float* conv_rW  = (const float*)d_in[12];
    const float* conv_b   = (const float*)d_in[13];
    const float* ln_scale = (const float*)d_in[14];
    const float* ln_bias  = (const float*)d_in[15];
    const float* lin1_W   = (const float*)d_in[16];
    const float* lin1_b   = (const float*)d_in[17];
    const float* lin2_W   = (const float*)d_in[18];
    const float* lin2_b   = (const float*)d_in[19];
    const float* readout_W= (const float*)d_in[20];
    float* out = (float*)d_out;

    unsigned char* ws = (unsigned char*)d_ws;
    float*  h_a    = (float*)(ws);                     // 1 MB
    float*  h_b    = (float*)(ws + 1048576);           // 1 MB
    float*  rkw    = (float*)(ws + 2097152);           // 128 KB
    __bf16* w1T    = (__bf16*)(ws + 2228224);          // 4 KB
    __bf16* w2T    = (__bf16*)(ws + 2232320);          // 4 KB
    __bf16* w2Tlo  = (__bf16*)(ws + 2236416);          // 4 KB
    __bf16* sWT    = (__bf16*)(ws + 2240512);          // 8 KB
    __bf16* sWTlo  = (__bf16*)(ws + 2248704);          // 8 KB
    float*  part16 = (float*)(ws + 2256896);           // 4 KB
    __bf16* kb_g   = (__bf16*)(ws + 2260992);          // 32 MB (single-copy kb)

    const bool fast = (ws_size >= 2260992ull + 33554432ull);

    if (fast) {
        k_setup<<<1041, 256, 0, stream>>>(x, emb_W, h_a,
                                          rkb_W1, rkb_b1, rkb_W2, rkb_b2, conv_rW, rkw,
                                          skb_W1, skb_W2, conv_sW,
                                          w1T, w2T, w2Tlo, sWT, sWTlo);
        k_kb2<<<2048, 256, 0, stream>>>(pos, skb_b1, skb_b2, w1T, w2T, w2Tlo, kb_g);
        k_conv8<<<256, 1024, 0, stream>>>(kb_g, sWT, sWTlo, conv_b, rkw,
                                          ln_scale, ln_bias, lin1_W, lin1_b,
                                          lin2_W, lin2_b, h_a, h_b, 0);
        k_conv8<<<256, 1024, 0, stream>>>(kb_g, sWT, sWTlo, conv_b, rkw,
                                          ln_scale, ln_bias, lin1_W, lin1_b,
                                          lin2_W, lin2_b, h_b, h_a, 1);
        k_readout_part2<<<16, 256, 0, stream>>>(h_a, part16);
        k_readout_final<<<1, 64, 0, stream>>>(part16, readout_W, out);
    } else {
        k_prep<<<1, 256, 0, stream>>>(skb_W1, skb_W2, conv_sW, w1T, w2T, w2Tlo, sWT, sWTlo);
        k_fiber2<<<16, 256, 0, stream>>>(rkb_W1, rkb_b1, rkb_W2, rkb_b2, conv_rW, rkw);
        k_init<<<1024, 256, 0, stream>>>(x, emb_W, h_a);
        k_layer2<<<256, 512, 0, stream>>>(pos, skb_b1, skb_b2, w1T, w2T, w2Tlo, sWT, sWTlo,
                                          conv_b, rkw, ln_scale, ln_bias, lin1_W, lin1_b,
                                          lin2_W, lin2_b, h_a, h_b, 0);
        k_layer2<<<256, 512, 0, stream>>>(pos, skb_b1, skb_b2, w1T, w2T, w2Tlo, sWT, sWTlo,
                                          conv_b, rkw, ln_scale, ln_bias, lin1_W, lin1_b,
                                          lin2_W, lin2_b, h_b, h_a, 1);
        k_readout_part<<<16, 256, 0, stream>>>(h_a, part16);
        k_readout_final<<<1, 64, 0, stream>>>(part16, readout_W, out);
    }
}